// Round 1
// baseline (193.736 us; speedup 1.0000x reference)
//
#include <hip/hip_runtime.h>

// SWD18: per-feature cyclic-shifted window-of-5 sort.
// Algebraic reduction: out[b, (w*5+j+i)%L, i] = sorted_j { v[b, (w*5+j+i)%L, i] }
// i.e. in-place sort of 5 cyclically-consecutive seq positions per feature,
// window grid offset by (i % 5). q, k inputs are unused by the reference.

constexpr int L = 4000;
constexpr int D = 512;

__global__ __launch_bounds__(256)
void swd18_window_sort(const float* __restrict__ v, float* __restrict__ out) {
    const int i = blockIdx.y * 256 + threadIdx.x;   // feature 0..511
    const int w = blockIdx.x;                       // window 0..799
    const int b = blockIdx.z;                       // batch

    const int r = i % 5;
    const int s = w * 5 + r;                        // window start row (never >= L)

    const float* __restrict__ vb = v + (size_t)b * (size_t)(L * D);
    float*       __restrict__ ob = out + (size_t)b * (size_t)(L * D);

    // rows of this window; only the last window (w==L/5-1, r>0) wraps
    int t0 = s;
    int t1 = s + 1; if (t1 >= L) t1 -= L;
    int t2 = s + 2; if (t2 >= L) t2 -= L;
    int t3 = s + 3; if (t3 >= L) t3 -= L;
    int t4 = s + 4; if (t4 >= L) t4 -= L;

    float x0 = vb[t0 * D + i];
    float x1 = vb[t1 * D + i];
    float x2 = vb[t2 * D + i];
    float x3 = vb[t3 * D + i];
    float x4 = vb[t4 * D + i];

    // optimal 9-comparator sorting network for 5 elements (ascending)
#define CE(a, b) { float lo_ = fminf(a, b); float hi_ = fmaxf(a, b); a = lo_; b = hi_; }
    CE(x0, x1) CE(x3, x4) CE(x2, x4) CE(x2, x3) CE(x1, x4)
    CE(x0, x3) CE(x0, x2) CE(x1, x3) CE(x1, x2)
#undef CE

    ob[t0 * D + i] = x0;
    ob[t1 * D + i] = x1;
    ob[t2 * D + i] = x2;
    ob[t3 * D + i] = x3;
    ob[t4 * D + i] = x4;
}

extern "C" void kernel_launch(void* const* d_in, const int* in_sizes, int n_in,
                              void* d_out, int out_size, void* d_ws, size_t ws_size,
                              hipStream_t stream) {
    // setup_inputs order: q, k, v  — only v is used by the reference forward.
    const float* v = (const float*)d_in[2];
    float* out = (float*)d_out;

    const int B = in_sizes[2] / (L * D);            // 8 for the bench shape

    dim3 grid(L / 5, D / 256, B);                   // 800 x 2 x B blocks
    swd18_window_sort<<<grid, dim3(256), 0, stream>>>(v, out);
}

// Round 2
// 184.020 us; speedup vs baseline: 1.0528x; 1.0528x over previous
//
#include <hip/hip_runtime.h>

// SWD18: per-feature cyclic-shifted window-of-5 sort.
// Algebraic reduction (verified absmax=0 in R1): for each feature i, sort
// groups of 5 cyclically-consecutive seq positions in place, window grid
// offset by (i % 5). q, k inputs are dead.
//
// R2: LDS-tiled version. R1's direct version scattered every vmem instruction
// across 5 rows / stride-5 cols -> WRITE_SIZE 1.76x ideal, 41% HBM BW.
// Here: float4-coalesced load of a 48-row x 128-col tile into LDS, stride-5
// window sorts inside LDS (bank = col%32 -> 2-way aliasing, free), then
// float4-coalesced store of rows [R0, R0+40) only. Each tile redundantly
// sorts the window straddling its lower edge so ALL its output rows are
// complete -> zero partial-line stores, every output element written exactly
// once device-wide.

constexpr int L = 4000;
constexpr int D = 512;
constexpr int TROWS = 40;            // output rows per tile (multiple of 5; 100 tiles)
constexpr int RROWS = 48;            // rows read: [R0-4, R0+44)
constexpr int CCOLS = 128;           // feature columns per tile
constexpr int NTHREADS = 256;

__global__ __launch_bounds__(NTHREADS)
void swd18_tile_sort(const float* __restrict__ v, float* __restrict__ out) {
    __shared__ float tile[RROWS * CCOLS];          // 24576 B -> ~6 blocks/CU

    const int tid = threadIdx.x;
    const int w   = blockIdx.x;                    // tile 0..99
    const int C0  = blockIdx.y * CCOLS;            // 0,128,256,384
    const int b   = blockIdx.z;
    const int R0  = w * TROWS;                     // multiple of 5

    const float* __restrict__ vb = v   + (size_t)b * (L * D) + C0;
    float*       __restrict__ ob = out + (size_t)b * (L * D) + C0;

    // ---- Phase 1: load rows [R0-4, R0+44) x 128 cols, float4-coalesced ----
    for (int idx = tid; idx < RROWS * (CCOLS / 4); idx += NTHREADS) {
        int lr = idx >> 5;                         // local row 0..47
        int c4 = (idx & 31) << 2;                  // col 0,4,...,124
        int g  = R0 - 4 + lr;                      // global row, may wrap
        if (g < 0)  g += L;
        if (g >= L) g -= L;
        float4 val = *(const float4*)(vb + (size_t)g * D + c4);
        *(float4*)(&tile[lr * CCOLS + c4]) = val;
    }
    __syncthreads();

    // ---- Phase 2: sort windows in LDS.
    // Per column (global residue r = gcol % 5), window local starts are
    // ls = r - 1 + 5k, k = 0..8 (skip ls < 0, i.e. r==0,k==0). This covers
    // every window touching output rows [R0, R0+40); spans stay within the
    // 48 loaded rows (max ls+4 = 47).
    for (int id = tid; id < 9 * CCOLS; id += NTHREADS) {
        int col = id & (CCOLS - 1);
        int k   = id >> 7;                         // 0..8
        int r   = (C0 + col) % 5;
        int ls  = r - 1 + 5 * k;
        if (ls < 0) continue;
        float* p = &tile[ls * CCOLS + col];
        float x0 = p[0 * CCOLS];
        float x1 = p[1 * CCOLS];
        float x2 = p[2 * CCOLS];
        float x3 = p[3 * CCOLS];
        float x4 = p[4 * CCOLS];
        // optimal 9-comparator sorting network, ascending
#define CE(a, b) { float lo_ = fminf(a, b); float hi_ = fmaxf(a, b); a = lo_; b = hi_; }
        CE(x0, x1) CE(x3, x4) CE(x2, x4) CE(x2, x3) CE(x1, x4)
        CE(x0, x3) CE(x0, x2) CE(x1, x3) CE(x1, x2)
#undef CE
        p[0 * CCOLS] = x0;
        p[1 * CCOLS] = x1;
        p[2 * CCOLS] = x2;
        p[3 * CCOLS] = x3;
        p[4 * CCOLS] = x4;
    }
    __syncthreads();

    // ---- Phase 3: store rows [R0, R0+40) (local 4..43), float4-coalesced ----
    for (int idx = tid; idx < TROWS * (CCOLS / 4); idx += NTHREADS) {
        int lr = (idx >> 5) + 4;                   // local row 4..43
        int c4 = (idx & 31) << 2;
        int g  = R0 + lr - 4;                      // in [0, L), never wraps
        *(float4*)(ob + (size_t)g * D + c4) = *(const float4*)(&tile[lr * CCOLS + c4]);
    }
}

extern "C" void kernel_launch(void* const* d_in, const int* in_sizes, int n_in,
                              void* d_out, int out_size, void* d_ws, size_t ws_size,
                              hipStream_t stream) {
    // setup_inputs order: q, k, v — only v is used by the reference forward.
    const float* v = (const float*)d_in[2];
    float* out = (float*)d_out;

    const int B = in_sizes[2] / (L * D);           // 8 for the bench shape

    dim3 grid(L / TROWS, D / CCOLS, B);            // 100 x 4 x B = 3200 blocks
    swd18_tile_sort<<<grid, dim3(NTHREADS), 0, stream>>>(v, out);
}